// Round 1
// 750.491 us; speedup vs baseline: 1.1615x; 1.1615x over previous
//
#include <hip/hip_runtime.h>

typedef __bf16 bf16;
typedef __bf16 bf16x8 __attribute__((ext_vector_type(8)));
typedef __bf16 bf16x4 __attribute__((ext_vector_type(4)));
typedef float  f32x4  __attribute__((ext_vector_type(4)));

// async global -> LDS, 16B per lane (lds dest = wave-uniform base + lane*16)
__device__ __forceinline__ void async_copy16(const bf16* g, bf16* l) {
    __builtin_amdgcn_global_load_lds(
        (const __attribute__((address_space(1))) unsigned int*)g,
        (__attribute__((address_space(3))) unsigned int*)l, 16, 0, 0);
}

// ---------------------------------------------------------------------------
// cast fp32 -> bf16, 8 elems/thread
// ---------------------------------------------------------------------------
__global__ __launch_bounds__(256) void cast_bf16(const float* __restrict__ src,
                                                 bf16* __restrict__ dst,
                                                 long long n) {
    long long i = ((long long)blockIdx.x * 256 + threadIdx.x) * 8;
    if (i >= n) return;
    float4 v0 = *(const float4*)&src[i];
    float4 v1 = *(const float4*)&src[i + 4];
    union { int4 v; bf16 h[8]; } u;
    u.h[0] = (bf16)v0.x; u.h[1] = (bf16)v0.y; u.h[2] = (bf16)v0.z; u.h[3] = (bf16)v0.w;
    u.h[4] = (bf16)v1.x; u.h[5] = (bf16)v1.y; u.h[6] = (bf16)v1.z; u.h[7] = (bf16)v1.w;
    *(int4*)&dst[i] = u.v;
}

// ---------------------------------------------------------------------------
// GEMM 256x256 tile, BK=32, 4-deep LDS pipeline (128KB), counted vmcnt.
// C[M,N] = A[M,K] @ B[N,K]^T, bf16 in, fp32 acc.
// 512 threads = 8 waves (2M x 4N), per-wave 128x64 output (8x4 16x16 frags).
// Schedule per K-tile: 2 phases x {ds_read; stage(t+3); bar; 16 MFMA; bar},
// boundary s_waitcnt vmcnt(8) (in-order retirement => tile t+1 landed,
// tiles t+2,t+3 stay in flight). LDS col swizzled col^=8*((row>>1)&3):
// inverse-swizzled global source (linear global_load_lds dest) + swizzled
// ds_read => 2-way (free) bank access.
// Requires M%256==0, N%256==0, K%32==0, K/32 >= 4.
// ---------------------------------------------------------------------------
template <typename OutT>
__global__ __launch_bounds__(512, 2) void gemm256(const bf16* __restrict__ A,
                                                  const bf16* __restrict__ B,
                                                  OutT* __restrict__ C,
                                                  int M, int N, int K) {
    // [buf0..3: A 256x32][buf0..3: B 256x32] = 65536 bf16 = 128KB
    __shared__ __attribute__((aligned(16))) bf16 sm[65536];

    const int tid = threadIdx.x, lane = tid & 63, w = tid >> 6;
    const int l16 = lane & 15, quad = lane >> 4;
    const int wr = w >> 2, wc = w & 3;            // 2M x 4N wave grid
    const int m0 = blockIdx.y * 256, n0 = blockIdx.x * 256;

    // staging geometry: issue i covers rows (i*8+w)*16 .. +16 of the tile.
    // lane covers row (lane>>2), 16B slot (lane&3); source col pre-swizzled.
    const int srow = lane >> 2;
    const int scol = 8 * ((lane & 3) ^ ((lane >> 3) & 3));
    const bf16* gA0 = A + (size_t)(m0 + w * 16 + srow) * K + scol;
    const bf16* gA1 = A + (size_t)(m0 + (8 + w) * 16 + srow) * K + scol;
    const bf16* gB0 = B + (size_t)(n0 + w * 16 + srow) * K + scol;
    const bf16* gB1 = B + (size_t)(n0 + (8 + w) * 16 + srow) * K + scol;

    // ds_read column (element) with matching swizzle; same for A and B reads
    const int rcol = 8 * (quad ^ ((l16 >> 1) & 3));

    f32x4 acc[8][4];
#pragma unroll
    for (int mi = 0; mi < 8; ++mi)
#pragma unroll
        for (int ni = 0; ni < 4; ++ni)
            acc[mi][ni] = f32x4{0.f, 0.f, 0.f, 0.f};

    const int NT = K >> 5;

    // prologue: stage tiles 0,1,2 (12 issues/wave); tile0 landed after vmcnt(8)
    for (int pt = 0; pt < 3; ++pt) {
        bf16* sa = &sm[pt * 8192];
        bf16* sb = &sm[32768 + pt * 8192];
        const int ko = pt * 32;
        async_copy16(gA0 + ko, sa + w * 512 + lane * 8);
        async_copy16(gB0 + ko, sb + w * 512 + lane * 8);
        async_copy16(gA1 + ko, sa + (8 + w) * 512 + lane * 8);
        async_copy16(gB1 + ko, sb + (8 + w) * 512 + lane * 8);
    }
    asm volatile("s_waitcnt vmcnt(8)" ::: "memory");
    __builtin_amdgcn_s_barrier();
    __builtin_amdgcn_sched_barrier(0);

#define GTILE(T, DO_STAGE, VMN)                                                   \
    {                                                                             \
        const int q_ = (T) & 3;                                                   \
        const bf16* a_ = &sm[q_ * 8192];                                          \
        const bf16* b_ = &sm[32768 + q_ * 8192];                                  \
        bf16x8 af[8], bf0, bf1;                                                   \
        _Pragma("unroll")                                                         \
        for (int mi = 0; mi < 8; ++mi)                                            \
            af[mi] = *(const bf16x8*)&a_[(wr * 128 + mi * 16 + l16) * 32 + rcol]; \
        bf0 = *(const bf16x8*)&b_[(wc * 64 + l16) * 32 + rcol];                   \
        bf1 = *(const bf16x8*)&b_[(wc * 64 + 16 + l16) * 32 + rcol];              \
        if (DO_STAGE) {                                                           \
            const int ko_ = ((T) + 3) * 32;                                       \
            bf16* sa_ = &sm[(((T) + 3) & 3) * 8192];                              \
            bf16* sb_ = &sm[32768 + (((T) + 3) & 3) * 8192];                      \
            async_copy16(gA0 + ko_, sa_ + w * 512 + lane * 8);                    \
            async_copy16(gB0 + ko_, sb_ + w * 512 + lane * 8);                    \
        }                                                                         \
        __builtin_amdgcn_s_barrier();                                             \
        __builtin_amdgcn_sched_barrier(0);                                        \
        __builtin_amdgcn_s_setprio(1);                                            \
        _Pragma("unroll")                                                         \
        for (int mi = 0; mi < 8; ++mi) {                                          \
            acc[mi][0] = __builtin_amdgcn_mfma_f32_16x16x32_bf16(af[mi], bf0,     \
                                                       acc[mi][0], 0, 0, 0);      \
            acc[mi][1] = __builtin_amdgcn_mfma_f32_16x16x32_bf16(af[mi], bf1,     \
                                                       acc[mi][1], 0, 0, 0);      \
        }                                                                         \
        __builtin_amdgcn_s_setprio(0);                                            \
        __builtin_amdgcn_s_barrier();                                             \
        __builtin_amdgcn_sched_barrier(0);                                        \
        bf0 = *(const bf16x8*)&b_[(wc * 64 + 32 + l16) * 32 + rcol];              \
        bf1 = *(const bf16x8*)&b_[(wc * 64 + 48 + l16) * 32 + rcol];              \
        if (DO_STAGE) {                                                           \
            const int ko_ = ((T) + 3) * 32;                                       \
            bf16* sa_ = &sm[(((T) + 3) & 3) * 8192];                              \
            bf16* sb_ = &sm[32768 + (((T) + 3) & 3) * 8192];                      \
            async_copy16(gA1 + ko_, sa_ + (8 + w) * 512 + lane * 8);              \
            async_copy16(gB1 + ko_, sb_ + (8 + w) * 512 + lane * 8);              \
        }                                                                         \
        __builtin_amdgcn_s_barrier();                                             \
        __builtin_amdgcn_sched_barrier(0);                                        \
        __builtin_amdgcn_s_setprio(1);                                            \
        _Pragma("unroll")                                                         \
        for (int mi = 0; mi < 8; ++mi) {                                          \
            acc[mi][2] = __builtin_amdgcn_mfma_f32_16x16x32_bf16(af[mi], bf0,     \
                                                       acc[mi][2], 0, 0, 0);      \
            acc[mi][3] = __builtin_amdgcn_mfma_f32_16x16x32_bf16(af[mi], bf1,     \
                                                       acc[mi][3], 0, 0, 0);      \
        }                                                                         \
        __builtin_amdgcn_s_setprio(0);                                            \
        asm volatile("s_waitcnt vmcnt(" #VMN ")" ::: "memory");                   \
        __builtin_amdgcn_s_barrier();                                             \
        __builtin_amdgcn_sched_barrier(0);                                        \
    }

    for (int t = 0; t < NT - 3; ++t) GTILE(t, 1, 8)
    GTILE(NT - 3, 0, 4)
    GTILE(NT - 2, 0, 0)
    GTILE(NT - 1, 0, 0)
#undef GTILE

    // epilogue: same verified C/D mapping as m97 (row = quad*4+r, col = l16)
#pragma unroll
    for (int mi = 0; mi < 8; ++mi)
#pragma unroll
        for (int ni = 0; ni < 4; ++ni) {
            int col = n0 + wc * 64 + ni * 16 + l16;
#pragma unroll
            for (int r = 0; r < 4; ++r) {
                int row = m0 + wr * 128 + mi * 16 + quad * 4 + r;
                C[(size_t)row * N + col] = (OutT)acc[mi][ni][r];
            }
        }
}

// ---------------------------------------------------------------------------
// Fused QK RMSNorm + RoPE
// ---------------------------------------------------------------------------
__global__ __launch_bounds__(256) void rmsnorm_rope(const bf16* __restrict__ qkv,
                                                    const float* __restrict__ qw,
                                                    const float* __restrict__ kw,
                                                    bf16* __restrict__ qb,
                                                    bf16* __restrict__ kb) {
    const int lane = threadIdx.x & 63, w = threadIdx.x >> 6;
    const int j = blockIdx.y * 4 + w;
    const int t = blockIdx.x;
    const int b = t >> 11, s = t & 2047;
    const bool isq = (j < 32);
    const bf16* src = qkv + (size_t)t * 6144 + (isq ? j * 128 : 4096 + (j - 32) * 128);
    float a  = (float)src[lane];
    float bb = (float)src[lane + 64];
    float ss = a * a + bb * bb;
    for (int off = 1; off < 64; off <<= 1) ss += __shfl_xor(ss, off, 64);
    float rms = rsqrtf(ss * (1.f / 128.f) + 1e-6f);
    const float* wn = isq ? qw : kw;
    float an = a * rms * wn[lane];
    float bn = bb * rms * wn[lane + 64];
    float inv_freq = exp2f(-(float)lane * (13.287712379549449f / 64.f));
    float fr = (float)s * inv_freq;
    float c = cosf(fr), sn = sinf(fr);
    float o0 = an * c - bn * sn;
    float o1 = bn * c + an * sn;
    if (isq) {
        const float sc = 0.08838834764831845f * 1.4426950408889634f; // 1/sqrt(128)*log2e
        o0 *= sc; o1 *= sc;
    }
    bf16* dst = isq ? (qb + (((size_t)(b * 32 + j)) * 2048 + s) * 128)
                    : (kb + (((size_t)(b * 8 + (j - 32))) * 2048 + s) * 128);
    dst[lane]      = (bf16)o0;
    dst[lane + 64] = (bf16)o1;
}

// ---------------------------------------------------------------------------
// V transpose: QKV[:, 5120+kvh*128+d] -> vb[b][kvh][d][s]
// ---------------------------------------------------------------------------
__global__ __launch_bounds__(256) void v_transpose(const bf16* __restrict__ qkv,
                                                   bf16* __restrict__ vb) {
    __shared__ __attribute__((aligned(16))) bf16 tile[64][130];
    const int tid = threadIdx.x;
    const int tt = blockIdx.x, kvh = blockIdx.y, b = blockIdx.z;
    const bf16* src = qkv + ((size_t)(b * 2048 + tt * 64)) * 6144 + 5120 + kvh * 128;
    for (int i = 0; i < 4; ++i) {
        int idx = tid + i * 256;
        int r = idx >> 4, c8 = (idx & 15) * 8;
        union { int4 v; bf16 h[8]; } u;
        u.v = *(const int4*)&src[(size_t)r * 6144 + c8];
        for (int jj = 0; jj < 8; ++jj) tile[r][c8 + jj] = u.h[jj];
    }
    __syncthreads();
    bf16* dst = vb + ((size_t)(b * 8 + kvh) * 128) * 2048 + tt * 64;
    for (int i = 0; i < 4; ++i) {
        int idx = tid + i * 256;
        int d = idx >> 3, r8 = (idx & 7) * 8;
        union { int4 v; bf16 h[8]; } u;
        for (int jj = 0; jj < 8; ++jj) u.h[jj] = tile[r8 + jj][d];
        *(int4*)&dst[(size_t)d * 2048 + r8] = u.v;
    }
}

// ---------------------------------------------------------------------------
// Flash attention v3: S^T formulation, TWO Q-heads per block (GQA sharing).
// Both heads (h0=2*hp, h0+1) use the same kvh = h0>>2, so one K/V staging and
// each LDS fragment load feeds two MFMAs. K rows staged bit-permuted:
// prow(rho) = rho5 | quad*8 | (mi&1)*4 | r  => S^T C-layout is directly the
// PV B-operand. Q pre-scaled by 1/sqrt(128)*log2e -> exp2 softmax.
// ---------------------------------------------------------------------------
__global__ __launch_bounds__(256, 2) void flash_kernel(const bf16* __restrict__ qb,
                                                       const bf16* __restrict__ kb,
                                                       const bf16* __restrict__ vb,
                                                       bf16* __restrict__ attnb) {
    const int S = 2048;
    const int hp = blockIdx.x;          // 0..15 head pair
    const int qt = 31 - blockIdx.y;     // heavy blocks dispatch first
    const int b  = blockIdx.z;
    const int h0 = hp * 2, kvh = h0 >> 2;
    const int tid = threadIdx.x, lane = tid & 63, w = tid >> 6;
    const int l16 = lane & 15, quad = lane >> 4;

    __shared__ __attribute__((aligned(16))) bf16 lK[64 * 128];   // [kv'][hd]
    __shared__ __attribute__((aligned(16))) bf16 lVt[128 * 64];  // [hd][kv]

    // Q fragments in registers for both heads: q-row = w*16 + l16
    const bf16* Qg0 = qb + (((size_t)(b * 32 + h0)) * S + qt * 64 + w * 16 + l16) * 128;
    const bf16* Qg1 = Qg0 + (size_t)S * 128;
    bf16x8 qf0[4], qf1[4];
    for (int c = 0; c < 4; ++c) {
        qf0[c] = *(const bf16x8*)&Qg0[c * 32 + quad * 8];
        qf1[c] = *(const bf16x8*)&Qg1[c * 32 + quad * 8];
    }

    const bf16* Kg = kb + ((size_t)(b * 8 + kvh)) * S * 128;
    const bf16* Vg = vb + ((size_t)(b * 8 + kvh)) * 128 * S;  // [128][S]

    int kOff[4], vOff[4];
    bf16 *kDst[4], *vDst[4];
    for (int i = 0; i < 4; ++i) {
        int c = w * 4 + i;
        int rho = c * 4 + (lane >> 4);
        int prow = (rho & 32) | ((rho & 12) << 1) | ((rho & 16) >> 2) | (rho & 3);
        kOff[i] = prow * 128 + (lane & 15) * 8;
        kDst[i] = lK + c * 512 + lane * 8;
        int d = c * 8 + (lane >> 3);
        vOff[i] = d * S + (lane & 7) * 8;
        vDst[i] = lVt + c * 512 + lane * 8;
    }

    float m0_i = -INFINITY, l0_i = 0.f, m1_i = -INFINITY, l1_i = 0.f;
    f32x4 O0[8], O1[8];                  // O^T: d = ti*16+quad*4+r, q = l16
    for (int ti = 0; ti < 8; ++ti) { O0[ti] = f32x4{0.f,0.f,0.f,0.f}; O1[ti] = f32x4{0.f,0.f,0.f,0.f}; }

    for (int kt = 0; kt <= qt; ++kt) {
        const bf16* Kt = Kg + (size_t)kt * 64 * 128;
        const bf16* Vt = Vg + kt * 64;
        for (int i = 0; i < 4; ++i) async_copy16(Kt + kOff[i], kDst[i]);
        for (int i = 0; i < 4; ++i) async_copy16(Vt + vOff[i], vDst[i]);
        __syncthreads();

        // S^T = K' Q^T for both heads, sharing kf loads
        f32x4 sT0[4], sT1[4];
        for (int mi = 0; mi < 4; ++mi) { sT0[mi] = f32x4{0.f,0.f,0.f,0.f}; sT1[mi] = f32x4{0.f,0.f,0.f,0.f}; }
        for (int mi = 0; mi < 4; ++mi)
            for (int c = 0; c < 4; ++c) {
                bf16x8 kf = *(const bf16x8*)&lK[(mi * 16 + l16) * 128 + c * 32 + quad * 8];
                sT0[mi] = __builtin_amdgcn_mfma_f32_16x16x32_bf16(kf, qf0[c], sT0[mi], 0, 0, 0);
                sT1[mi] = __builtin_amdgcn_mfma_f32_16x16x32_bf16(kf, qf1[c], sT1[mi], 0, 0, 0);
            }

        if (kt == qt) {  // causal mask on diagonal tile (kv in permuted coords)
            int qloc = w * 16 + l16;
            for (int mi = 0; mi < 4; ++mi) {
                int kvbase = (mi >> 1) * 32 + quad * 8 + (mi & 1) * 4;
                for (int r = 0; r < 4; ++r)
                    if (kvbase + r > qloc) { sT0[mi][r] = -INFINITY; sT1[mi][r] = -INFINITY; }
            }
        }

        // online softmax (both heads, independent -> ILP)
        float mx0 = sT0[0][0], mx1 = sT1[0][0];
        for (int mi = 0; mi < 4; ++mi)
            for (int r = 0; r < 4; ++r) { mx0 = fmaxf(mx0, sT0[mi][r]); mx1 = fmaxf(mx1, sT1[mi][r]); }
        mx0 = fmaxf(mx0, __shfl_xor(mx0, 16, 64));
        mx0 = fmaxf(mx0, __shfl_xor(mx0, 32, 64));
        mx1 = fmaxf(mx1, __shfl_xor(mx1, 16, 64));
        mx1 = fmaxf(mx1, __shfl_xor(mx1, 32, 64));
        float mn0 = fmaxf(m0_i, mx0), mn1 = fmaxf(m1_i, mx1);
        float al0 = exp2f(m0_i - mn0), al1 = exp2f(m1_i - mn1);
        m0_i = mn0; m1_i = mn1;

        bf16x8 pbt0[2], pbt1[2];
        float s0 = 0.f, s1 = 0.f;
        for (int mi = 0; mi < 4; ++mi) {
            int t = mi >> 1, o = (mi & 1) * 4;
            for (int r = 0; r < 4; ++r) {
                float p0 = exp2f(sT0[mi][r] - mn0);
                float p1 = exp2f(sT1[mi][r] - mn1);
                s0 += p0; s1 += p1;
                pbt0[t][o + r] = (bf16)p0;
                pbt1[t][o + r] = (bf16)p1;
            }
        }
        s0 += __shfl_xor(s0, 16, 64); s0 += __shfl_xor(s0, 32, 64);
        s1 += __shfl_xor(s1, 16, 64); s1 += __shfl_xor(s1, 32, 64);
        l0_i = l0_i * al0 + s0;
        l1_i = l1_i * al1 + s1;
        for (int ti = 0; ti < 8; ++ti) { O0[ti] *= al0; O1[ti] *= al1; }

        // O^T += V^T P^T, sharing vf loads
        for (int ti = 0; ti < 8; ++ti)
            for (int t = 0; t < 2; ++t) {
                bf16x8 vf = *(const bf16x8*)&lVt[(ti * 16 + l16) * 64 + t * 32 + quad * 8];
                O0[ti] = __builtin_amdgcn_mfma_f32_16x16x32_bf16(vf, pbt0[t], O0[ti], 0, 0, 0);
                O1[ti] = __builtin_amdgcn_mfma_f32_16x16x32_bf16(vf, pbt1[t], O1[ti], 0, 0, 0);
            }
        __syncthreads();
    }

    // epilogue: attn[b][s][h*128 + d], 8B packed stores, both heads
    float i0 = 1.f / l0_i, i1 = 1.f / l1_i;
    bf16* dst = attnb + (((size_t)(b * S + qt * 64 + w * 16 + l16)) * 4096) + h0 * 128 + quad * 4;
    for (int ti = 0; ti < 8; ++ti) {
        bf16x4 o4, o5;
        for (int r = 0; r < 4; ++r) { o4[r] = (bf16)(O0[ti][r] * i0); o5[r] = (bf16)(O1[ti][r] * i1); }
        *(bf16x4*)&dst[ti * 16] = o4;
        *(bf16x4*)&dst[128 + ti * 16] = o5;
    }
}

// ---------------------------------------------------------------------------
// launch
// ---------------------------------------------------------------------------
extern "C" void kernel_launch(void* const* d_in, const int* in_sizes, int n_in,
                              void* d_out, int out_size, void* d_ws, size_t ws_size,
                              hipStream_t stream) {
    const float* X  = (const float*)d_in[0];
    const float* Wq = (const float*)d_in[2];
    const float* Wk = (const float*)d_in[3];
    const float* Wv = (const float*)d_in[4];
    const float* Wo = (const float*)d_in[5];
    const float* qw = (const float*)d_in[6];
    const float* kw = (const float*)d_in[7];
    float* out = (float*)d_out;
    char* ws = (char*)d_ws;

    bf16* Xb    = (bf16*)(ws);                 // [0,32M)
    bf16* Wqkvb = (bf16*)(ws + 33554432);      // [32M,80M)
    bf16* QKVb  = (bf16*)(ws + 83886080);      // [80M,128M)
    bf16* qbuf  = (bf16*)(ws);                 // reuse Xb
    bf16* kbuf  = (bf16*)(ws + 33554432);      // reuse Wqkvb
    bf16* vbuf  = (bf16*)(ws + 41943040);
    bf16* Wob   = (bf16*)(ws + 50331648);
    bf16* attnb = (bf16*)(ws + 83886080);      // reuse QKVb

    cast_bf16<<<8192, 256, 0, stream>>>(X, Xb, 16777216);
    cast_bf16<<<8192, 256, 0, stream>>>(Wq, Wqkvb, 16777216);
    cast_bf16<<<2048, 256, 0, stream>>>(Wk, Wqkvb + 16777216, 4194304);
    cast_bf16<<<2048, 256, 0, stream>>>(Wv, Wqkvb + 20971520, 4194304);

    gemm256<bf16><<<dim3(24, 16), 512, 0, stream>>>(Xb, Wqkvb, QKVb, 4096, 6144, 4096);

    rmsnorm_rope<<<dim3(4096, 10), 256, 0, stream>>>(QKVb, qw, kw, qbuf, kbuf);
    v_transpose<<<dim3(32, 8, 2), 256, 0, stream>>>(QKVb, vbuf);
    cast_bf16<<<8192, 256, 0, stream>>>(Wo, Wob, 16777216);

    flash_kernel<<<dim3(16, 32, 2), 256, 0, stream>>>(qbuf, kbuf, vbuf, attnb);

    gemm256<float><<<dim3(16, 16), 512, 0, stream>>>(attnb, Wob, out, 4096, 4096, 4096);
}

// Round 3
// 731.589 us; speedup vs baseline: 1.1915x; 1.0258x over previous
//
#include <hip/hip_runtime.h>

typedef __bf16 bf16;
typedef __bf16 bf16x8 __attribute__((ext_vector_type(8)));
typedef __bf16 bf16x4 __attribute__((ext_vector_type(4)));
typedef float  f32x4  __attribute__((ext_vector_type(4)));

// async global -> LDS, 16B per lane (lds dest = wave-uniform base + lane*16)
__device__ __forceinline__ void async_copy16(const bf16* g, bf16* l) {
    __builtin_amdgcn_global_load_lds(
        (const __attribute__((address_space(1))) unsigned int*)g,
        (__attribute__((address_space(3))) unsigned int*)l, 16, 0, 0);
}

// ---------------------------------------------------------------------------
// cast fp32 -> bf16, 8 elems/thread
// ---------------------------------------------------------------------------
__global__ __launch_bounds__(256) void cast_bf16(const float* __restrict__ src,
                                                 bf16* __restrict__ dst,
                                                 long long n) {
    long long i = ((long long)blockIdx.x * 256 + threadIdx.x) * 8;
    if (i >= n) return;
    float4 v0 = *(const float4*)&src[i];
    float4 v1 = *(const float4*)&src[i + 4];
    union { int4 v; bf16 h[8]; } u;
    u.h[0] = (bf16)v0.x; u.h[1] = (bf16)v0.y; u.h[2] = (bf16)v0.z; u.h[3] = (bf16)v0.w;
    u.h[4] = (bf16)v1.x; u.h[5] = (bf16)v1.y; u.h[6] = (bf16)v1.z; u.h[7] = (bf16)v1.w;
    *(int4*)&dst[i] = u.v;
}

// ---------------------------------------------------------------------------
// GEMM, m201-style 8-phase schedule. C[M,N] = A[M,K] @ B[N,K]^T, bf16 in.
// 256x256 tile, BK=64 (K-step), 2 LDS buffers x (A 256x64 + B 256x64) = 128KB.
// 512 thr = 8 waves (2M x 4N), per-wave 128x64 out = acc[8][4] f32x4.
// Per K-step: 4 phases (C-quadrants m0n0, m0n1, m1n1, m1n0), each phase:
//   {ds_read subtile; stage one 16KB chunk; barrier; lgkmcnt(0); setprio(1);
//    16 MFMA; setprio(0); [ph4: vmcnt(6)]; barrier}
// Staging: ph1 -> B(n0) of step s+1 (other buf, region free since s-1.ph4);
// ph2/3/4 -> A(m0)/B(n1)/A(m1) of step s+2 into CURRENT buf's region freed
// by the previous phase's reads. vmcnt(6) at ph4 retires all of step s+1,
// keeps 3 chunks (step s+2) in flight. LDS 8-slot XOR swizzle (row&7) on
// stage source + ds_read addr -> 2-way (free) bank access.
// Requires M%256==0, N%256==0, K%64==0, K/64 >= 3.
// Buffer p: A at sm + p*32768, B at sm + 16384 + p*32768.
// ---------------------------------------------------------------------------
template <typename OutT>
__global__ __launch_bounds__(512, 2) void gemm8p(const bf16* __restrict__ A,
                                                 const bf16* __restrict__ B,
                                                 OutT* __restrict__ C,
                                                 int M, int N, int K) {
    __shared__ __attribute__((aligned(16))) bf16 sm[65536];  // 128 KB

    const int tid = threadIdx.x, lane = tid & 63, w = tid >> 6;
    const int l16 = lane & 15, quad = lane >> 4;
    const int wr = w >> 2, wc = w & 3;
    const int m0 = blockIdx.y * 256, n0 = blockIdx.x * 256;

    // staging: each issue = 1KB/wave = 8 rows x 128B; row-in-chunk = lane>>3,
    // 16B slot = lane&7, source col pre-swizzled by row&7 (= lane>>3)
    const int srow = lane >> 3;
    const int scol = 8 * ((lane & 7) ^ srow);
    const int rsw  = l16 & 7;  // ds_read swizzle key (row&7)

    f32x4 acc[8][4];
#pragma unroll
    for (int mi = 0; mi < 8; ++mi)
#pragma unroll
        for (int ni = 0; ni < 4; ++ni)
            acc[mi][ni] = f32x4{0.f, 0.f, 0.f, 0.f};

    const int NT = K >> 6;

    // --- stage helpers: 2 x global_load_lds per thread per call -------------
    auto stgA = [&](int h, bf16* la, int ko) {
        // region A(m_h): rows {h*64..h*64+63} u {128+h*64..128+h*64+63}
        const int r0 = h * 64 + w * 8;
        async_copy16(A + (size_t)(m0 + r0 + srow) * K + ko + scol,
                     la + r0 * 64 + lane * 8);
        const int r1 = 128 + h * 64 + w * 8;
        async_copy16(A + (size_t)(m0 + r1 + srow) * K + ko + scol,
                     la + r1 * 64 + lane * 8);
    };
    auto stgB = [&](int nh, bf16* lb, int ko) {
        // region B(n_nh): rows b*64 + nh*32 + {0..31}, b = 0..3
#pragma unroll
        for (int i = 0; i < 2; ++i) {
            int idx = i * 8 + w;
            int r = (idx >> 2) * 64 + nh * 32 + (idx & 3) * 8;
            async_copy16(B + (size_t)(n0 + r + srow) * K + ko + scol,
                         lb + r * 64 + lane * 8);
        }
    };

#define RDA(h)                                                                  \
    _Pragma("unroll") for (int i2 = 0; i2 < 4; ++i2)                            \
        _Pragma("unroll") for (int kk = 0; kk < 2; ++kk)                        \
            af[i2][kk] = *(const bf16x8*)&a_[(wr * 128 + ((h) * 4 + i2) * 16 +  \
                                              l16) * 64 +                       \
                                             8 * (((kk << 2) | quad) ^ rsw)];
#define RDB(nh)                                                                 \
    _Pragma("unroll") for (int j2 = 0; j2 < 2; ++j2)                            \
        _Pragma("unroll") for (int kk = 0; kk < 2; ++kk)                        \
            bfr[j2][kk] = *(const bf16x8*)&b_[(wc * 64 + ((nh) * 2 + j2) * 16 + \
                                               l16) * 64 +                      \
                                              8 * (((kk << 2) | quad) ^ rsw)];
#define MM(h, nh)                                                               \
    _Pragma("unroll") for (int i2 = 0; i2 < 4; ++i2)                            \
        _Pragma("unroll") for (int j2 = 0; j2 < 2; ++j2) {                      \
            acc[(h) * 4 + i2][(nh) * 2 + j2] =                                  \
                __builtin_amdgcn_mfma_f32_16x16x32_bf16(                        \
                    af[i2][0], bfr[j2][0], acc[(h) * 4 + i2][(nh) * 2 + j2],    \
                    0, 0, 0);                                                   \
            acc[(h) * 4 + i2][(nh) * 2 + j2] =                                  \
                __builtin_amdgcn_mfma_f32_16x16x32_bf16(                        \
                    af[i2][1], bfr[j2][1], acc[(h) * 4 + i2][(nh) * 2 + j2],    \
                    0, 0, 0);                                                   \
        }
#define FENCE_MFMA                                                              \
    __builtin_amdgcn_sched_barrier(0);                                          \
    __builtin_amdgcn_s_barrier();                                               \
    asm volatile("s_waitcnt lgkmcnt(0)" ::: "memory");                          \
    __builtin_amdgcn_sched_barrier(0);                                          \
    __builtin_amdgcn_s_setprio(1);
#define ENDPH                                                                   \
    __builtin_amdgcn_s_setprio(0);                                              \
    __builtin_amdgcn_sched_barrier(0);                                          \
    __builtin_amdgcn_s_barrier();                                               \
    __builtin_amdgcn_sched_barrier(0);

    // --- prologue: step0 (4 chunks) + step1 (Am0,Bn1,Am1) -------------------
    stgB(0, sm + 16384, 0); stgA(0, sm, 0); stgB(1, sm + 16384, 0); stgA(1, sm, 0);
    stgA(0, sm + 32768, 64); stgB(1, sm + 49152, 64); stgA(1, sm + 32768, 64);
    asm volatile("s_waitcnt vmcnt(6)" ::: "memory");
    __builtin_amdgcn_s_barrier();
    __builtin_amdgcn_sched_barrier(0);

    // --- main loop: steps 0..NT-3 full staging ------------------------------
    for (int s = 0; s < NT - 2; ++s) {
        const int p = s & 1;
        bf16* a_ = sm + p * 32768;
        bf16* b_ = sm + 16384 + p * 32768;
        bf16* aS = a_;
        bf16* bS = b_;
        bf16* bO = sm + 16384 + (1 - p) * 32768;
        const int ko1 = (s + 1) << 6, ko2 = (s + 2) << 6;
        bf16x8 af[4][2], bfr[2][2];

        RDA(0) RDB(0) stgB(0, bO, ko1);
        FENCE_MFMA; MM(0, 0) ENDPH;

        RDB(1) stgA(0, aS, ko2);
        FENCE_MFMA; MM(0, 1) ENDPH;

        RDA(1) stgB(1, bS, ko2);
        FENCE_MFMA; MM(1, 1) ENDPH;

        RDB(0) stgA(1, aS, ko2);
        FENCE_MFMA; MM(1, 0)
        __builtin_amdgcn_s_setprio(0);
        __builtin_amdgcn_sched_barrier(0);
        asm volatile("s_waitcnt vmcnt(6)" ::: "memory");
        __builtin_amdgcn_s_barrier();
        __builtin_amdgcn_sched_barrier(0);
    }

    // --- step NT-2: stage only B(n0) of NT-1; drain vmcnt(0) ----------------
    {
        const int p = (NT - 2) & 1;
        bf16* a_ = sm + p * 32768;
        bf16* b_ = sm + 16384 + p * 32768;
        bf16* bO = sm + 16384 + (1 - p) * 32768;
        const int ko1 = (NT - 1) << 6;
        bf16x8 af[4][2], bfr[2][2];

        RDA(0) RDB(0) stgB(0, bO, ko1);
        FENCE_MFMA; MM(0, 0) ENDPH;
        RDB(1)
        FENCE_MFMA; MM(0, 1) ENDPH;
        RDA(1)
        FENCE_MFMA; MM(1, 1) ENDPH;
        RDB(0)
        FENCE_MFMA; MM(1, 0)
        __builtin_amdgcn_s_setprio(0);
        __builtin_amdgcn_sched_barrier(0);
        asm volatile("s_waitcnt vmcnt(0)" ::: "memory");
        __builtin_amdgcn_s_barrier();
        __builtin_amdgcn_sched_barrier(0);
    }

    // --- step NT-1: no staging ----------------------------------------------
    {
        const int p = (NT - 1) & 1;
        bf16* a_ = sm + p * 32768;
        bf16* b_ = sm + 16384 + p * 32768;
        bf16x8 af[4][2], bfr[2][2];

        RDA(0) RDB(0)
        FENCE_MFMA; MM(0, 0) ENDPH;
        RDB(1)
        FENCE_MFMA; MM(0, 1) ENDPH;
        RDA(1)
        FENCE_MFMA; MM(1, 1) ENDPH;
        RDB(0)
        FENCE_MFMA; MM(1, 0)
        __builtin_amdgcn_s_setprio(0);
        __builtin_amdgcn_sched_barrier(0);
    }
#undef RDA
#undef RDB
#undef MM
#undef FENCE_MFMA
#undef ENDPH

    // epilogue: verified C/D mapping (row = quad*4+r, col = l16)
#pragma unroll
    for (int mi = 0; mi < 8; ++mi)
#pragma unroll
        for (int ni = 0; ni < 4; ++ni) {
            int col = n0 + wc * 64 + ni * 16 + l16;
#pragma unroll
            for (int r = 0; r < 4; ++r) {
                int row = m0 + wr * 128 + mi * 16 + quad * 4 + r;
                C[(size_t)row * N + col] = (OutT)acc[mi][ni][r];
            }
        }
}

// ---------------------------------------------------------------------------
// Fused QK RMSNorm + RoPE
// ---------------------------------------------------------------------------
__global__ __launch_bounds__(256) void rmsnorm_rope(const bf16* __restrict__ qkv,
                                                    const float* __restrict__ qw,
                                                    const float* __restrict__ kw,
                                                    bf16* __restrict__ qb,
                                                    bf16* __restrict__ kb) {
    const int lane = threadIdx.x & 63, w = threadIdx.x >> 6;
    const int j = blockIdx.y * 4 + w;
    const int t = blockIdx.x;
    const int b = t >> 11, s = t & 2047;
    const bool isq = (j < 32);
    const bf16* src = qkv + (size_t)t * 6144 + (isq ? j * 128 : 4096 + (j - 32) * 128);
    float a  = (float)src[lane];
    float bb = (float)src[lane + 64];
    float ss = a * a + bb * bb;
    for (int off = 1; off < 64; off <<= 1) ss += __shfl_xor(ss, off, 64);
    float rms = rsqrtf(ss * (1.f / 128.f) + 1e-6f);
    const float* wn = isq ? qw : kw;
    float an = a * rms * wn[lane];
    float bn = bb * rms * wn[lane + 64];
    float inv_freq = exp2f(-(float)lane * (13.287712379549449f / 64.f));
    float fr = (float)s * inv_freq;
    float c = cosf(fr), sn = sinf(fr);
    float o0 = an * c - bn * sn;
    float o1 = bn * c + an * sn;
    if (isq) {
        const float sc = 0.08838834764831845f * 1.4426950408889634f; // 1/sqrt(128)*log2e
        o0 *= sc; o1 *= sc;
    }
    bf16* dst = isq ? (qb + (((size_t)(b * 32 + j)) * 2048 + s) * 128)
                    : (kb + (((size_t)(b * 8 + (j - 32))) * 2048 + s) * 128);
    dst[lane]      = (bf16)o0;
    dst[lane + 64] = (bf16)o1;
}

// ---------------------------------------------------------------------------
// V transpose: QKV[:, 5120+kvh*128+d] -> vb[b][kvh][d][s]
// ---------------------------------------------------------------------------
__global__ __launch_bounds__(256) void v_transpose(const bf16* __restrict__ qkv,
                                                   bf16* __restrict__ vb) {
    __shared__ __attribute__((aligned(16))) bf16 tile[64][130];
    const int tid = threadIdx.x;
    const int tt = blockIdx.x, kvh = blockIdx.y, b = blockIdx.z;
    const bf16* src = qkv + ((size_t)(b * 2048 + tt * 64)) * 6144 + 5120 + kvh * 128;
    for (int i = 0; i < 4; ++i) {
        int idx = tid + i * 256;
        int r = idx >> 4, c8 = (idx & 15) * 8;
        union { int4 v; bf16 h[8]; } u;
        u.v = *(const int4*)&src[(size_t)r * 6144 + c8];
        for (int jj = 0; jj < 8; ++jj) tile[r][c8 + jj] = u.h[jj];
    }
    __syncthreads();
    bf16* dst = vb + ((size_t)(b * 8 + kvh) * 128) * 2048 + tt * 64;
    for (int i = 0; i < 4; ++i) {
        int idx = tid + i * 256;
        int d = idx >> 3, r8 = (idx & 7) * 8;
        union { int4 v; bf16 h[8]; } u;
        for (int jj = 0; jj < 8; ++jj) u.h[jj] = tile[r8 + jj][d];
        *(int4*)&dst[(size_t)d * 2048 + r8] = u.v;
    }
}

// ---------------------------------------------------------------------------
// Flash attention v3: S^T formulation, TWO Q-heads per block (GQA sharing).
// ---------------------------------------------------------------------------
__global__ __launch_bounds__(256, 2) void flash_kernel(const bf16* __restrict__ qb,
                                                       const bf16* __restrict__ kb,
                                                       const bf16* __restrict__ vb,
                                                       bf16* __restrict__ attnb) {
    const int S = 2048;
    const int hp = blockIdx.x;          // 0..15 head pair
    const int qt = 31 - blockIdx.y;     // heavy blocks dispatch first
    const int b  = blockIdx.z;
    const int h0 = hp * 2, kvh = h0 >> 2;
    const int tid = threadIdx.x, lane = tid & 63, w = tid >> 6;
    const int l16 = lane & 15, quad = lane >> 4;

    __shared__ __attribute__((aligned(16))) bf16 lK[64 * 128];   // [kv'][hd]
    __shared__ __attribute__((aligned(16))) bf16 lVt[128 * 64];  // [hd][kv]

    const bf16* Qg0 = qb + (((size_t)(b * 32 + h0)) * S + qt * 64 + w * 16 + l16) * 128;
    const bf16* Qg1 = Qg0 + (size_t)S * 128;
    bf16x8 qf0[4], qf1[4];
    for (int c = 0; c < 4; ++c) {
        qf0[c] = *(const bf16x8*)&Qg0[c * 32 + quad * 8];
        qf1[c] = *(const bf16x8*)&Qg1[c * 32 + quad * 8];
    }

    const bf16* Kg = kb + ((size_t)(b * 8 + kvh)) * S * 128;
    const bf16* Vg = vb + ((size_t)(b * 8 + kvh)) * 128 * S;  // [128][S]

    int kOff[4], vOff[4];
    bf16 *kDst[4], *vDst[4];
    for (int i = 0; i < 4; ++i) {
        int c = w * 4 + i;
        int rho = c * 4 + (lane >> 4);
        int prow = (rho & 32) | ((rho & 12) << 1) | ((rho & 16) >> 2) | (rho & 3);
        kOff[i] = prow * 128 + (lane & 15) * 8;
        kDst[i] = lK + c * 512 + lane * 8;
        int d = c * 8 + (lane >> 3);
        vOff[i] = d * S + (lane & 7) * 8;
        vDst[i] = lVt + c * 512 + lane * 8;
    }

    float m0_i = -INFINITY, l0_i = 0.f, m1_i = -INFINITY, l1_i = 0.f;
    f32x4 O0[8], O1[8];                  // O^T: d = ti*16+quad*4+r, q = l16
    for (int ti = 0; ti < 8; ++ti) { O0[ti] = f32x4{0.f,0.f,0.f,0.f}; O1[ti] = f32x4{0.f,0.f,0.f,0.f}; }

    for (int kt = 0; kt <= qt; ++kt) {
        const bf16* Kt = Kg + (size_t)kt * 64 * 128;
        const bf16* Vt = Vg + kt * 64;
        for (int i = 0; i < 4; ++i) async_copy16(Kt + kOff[i], kDst[i]);
        for (int i = 0; i < 4; ++i) async_copy16(Vt + vOff[i], vDst[i]);
        __syncthreads();

        f32x4 sT0[4], sT1[4];
        for (int mi = 0; mi < 4; ++mi) { sT0[mi] = f32x4{0.f,0.f,0.f,0.f}; sT1[mi] = f32x4{0.f,0.f,0.f,0.f}; }
        for (int mi = 0; mi < 4; ++mi)
            for (int c = 0; c < 4; ++c) {
                bf16x8 kf = *(const bf16x8*)&lK[(mi * 16 + l16) * 128 + c * 32 + quad * 8];
                sT0[mi] = __builtin_amdgcn_mfma_f32_16x16x32_bf16(kf, qf0[c], sT0[mi], 0, 0, 0);
                sT1[mi] = __builtin_amdgcn_mfma_f32_16x16x32_bf16(kf, qf1[c], sT1[mi], 0, 0, 0);
            }

        if (kt == qt) {  // causal mask on diagonal tile (kv in permuted coords)
            int qloc = w * 16 + l16;
            for (int mi = 0; mi < 4; ++mi) {
                int kvbase = (mi >> 1) * 32 + quad * 8 + (mi & 1) * 4;
                for (int r = 0; r < 4; ++r)
                    if (kvbase + r > qloc) { sT0[mi][r] = -INFINITY; sT1[mi][r] = -INFINITY; }
            }
        }

        float mx0 = sT0[0][0], mx1 = sT1[0][0];
        for (int mi = 0; mi < 4; ++mi)
            for (int r = 0; r < 4; ++r) { mx0 = fmaxf(mx0, sT0[mi][r]); mx1 = fmaxf(mx1, sT1[mi][r]); }
        mx0 = fmaxf(mx0, __shfl_xor(mx0, 16, 64));
        mx0 = fmaxf(mx0, __shfl_xor(mx0, 32, 64));
        mx1 = fmaxf(mx1, __shfl_xor(mx1, 16, 64));
        mx1 = fmaxf(mx1, __shfl_xor(mx1, 32, 64));
        float mn0 = fmaxf(m0_i, mx0), mn1 = fmaxf(m1_i, mx1);
        float al0 = exp2f(m0_i - mn0), al1 = exp2f(m1_i - mn1);
        m0_i = mn0; m1_i = mn1;

        bf16x8 pbt0[2], pbt1[2];
        float s0 = 0.f, s1 = 0.f;
        for (int mi = 0; mi < 4; ++mi) {
            int t = mi >> 1, o = (mi & 1) * 4;
            for (int r = 0; r < 4; ++r) {
                float p0 = exp2f(sT0[mi][r] - mn0);
                float p1 = exp2f(sT1[mi][r] - mn1);
                s0 += p0; s1 += p1;
                pbt0[t][o + r] = (bf16)p0;
                pbt1[t][o + r] = (bf16)p1;
            }
        }
        s0 += __shfl_xor(s0, 16, 64); s0 += __shfl_xor(s0, 32, 64);
        s1 += __shfl_xor(s1, 16, 64); s1 += __shfl_xor(s1, 32, 64);
        l0_i = l0_i * al0 + s0;
        l1_i = l1_i * al1 + s1;
        for (int ti = 0; ti < 8; ++ti) { O0[ti] *= al0; O1[ti] *= al1; }

        for (int ti = 0; ti < 8; ++ti)
            for (int t = 0; t < 2; ++t) {
                bf16x8 vf = *(const bf16x8*)&lVt[(ti * 16 + l16) * 64 + t * 32 + quad * 8];
                O0[ti] = __builtin_amdgcn_mfma_f32_16x16x32_bf16(vf, pbt0[t], O0[ti], 0, 0, 0);
                O1[ti] = __builtin_amdgcn_mfma_f32_16x16x32_bf16(vf, pbt1[t], O1[ti], 0, 0, 0);
            }
        __syncthreads();
    }

    float i0 = 1.f / l0_i, i1 = 1.f / l1_i;
    bf16* dst = attnb + (((size_t)(b * S + qt * 64 + w * 16 + l16)) * 4096) + h0 * 128 + quad * 4;
    for (int ti = 0; ti < 8; ++ti) {
        bf16x4 o4, o5;
        for (int r = 0; r < 4; ++r) { o4[r] = (bf16)(O0[ti][r] * i0); o5[r] = (bf16)(O1[ti][r] * i1); }
        *(bf16x4*)&dst[ti * 16] = o4;
        *(bf16x4*)&dst[128 + ti * 16] = o5;
    }
}

// ---------------------------------------------------------------------------
// launch
// ---------------------------------------------------------------------------
extern "C" void kernel_launch(void* const* d_in, const int* in_sizes, int n_in,
                              void* d_out, int out_size, void* d_ws, size_t ws_size,
                              hipStream_t stream) {
    const float* X  = (const float*)d_in[0];
    const float* Wq = (const float*)d_in[2];
    const float* Wk = (const float*)d_in[3];
    const float* Wv = (const float*)d_in[4];
    const float* Wo = (const float*)d_in[5];
    const float* qw = (const float*)d_in[6];
    const float* kw = (const float*)d_in[7];
    float* out = (float*)d_out;
    char* ws = (char*)d_ws;

    bf16* Xb    = (bf16*)(ws);                 // [0,32M)
    bf16* Wqkvb = (bf16*)(ws + 33554432);      // [32M,80M)
    bf16* QKVb  = (bf16*)(ws + 83886080);      // [80M,128M)
    bf16* qbuf  = (bf16*)(ws);                 // reuse Xb
    bf16* kbuf  = (bf16*)(ws + 33554432);      // reuse Wqkvb
    bf16* vbuf  = (bf16*)(ws + 41943040);
    bf16* Wob   = (bf16*)(ws + 50331648);
    bf16* attnb = (bf16*)(ws + 83886080);      // reuse QKVb

    cast_bf16<<<8192, 256, 0, stream>>>(X, Xb, 16777216);
    cast_bf16<<<8192, 256, 0, stream>>>(Wq, Wqkvb, 16777216);
    cast_bf16<<<2048, 256, 0, stream>>>(Wk, Wqkvb + 16777216, 4194304);
    cast_bf16<<<2048, 256, 0, stream>>>(Wv, Wqkvb + 20971520, 4194304);

    gemm8p<bf16><<<dim3(24, 16), 512, 0, stream>>>(Xb, Wqkvb, QKVb, 4096, 6144, 4096);

    rmsnorm_rope<<<dim3(4096, 10), 256, 0, stream>>>(QKVb, qw, kw, qbuf, kbuf);
    v_transpose<<<dim3(32, 8, 2), 256, 0, stream>>>(QKVb, vbuf);
    cast_bf16<<<8192, 256, 0, stream>>>(Wo, Wob, 16777216);

    flash_kernel<<<dim3(16, 32, 2), 256, 0, stream>>>(qbuf, kbuf, vbuf, attnb);

    gemm8p<float><<<dim3(16, 16), 512, 0, stream>>>(attnb, Wob, out, 4096, 4096, 4096);
}